// Round 5
// baseline (91.372 us; speedup 1.0000x reference)
//
#include <hip/hip_runtime.h>

typedef _Float16 f16;
typedef f16   f16x4 __attribute__((ext_vector_type(4)));
typedef f16   f16x8 __attribute__((ext_vector_type(8)));
typedef float f32x4 __attribute__((ext_vector_type(4)));

#define E 512            /* embed dim = K for both GEMMs */
#define BM 64            /* rows per block */
#define NT 16            /* K-steps of 32 */
#define NCHUNK 2         /* two 256-wide n(f)-chunks per phase */

// ---------------------------------------------------------------------------
// Weight convert: Wq, Wo (fp32 [512][512]) -> f16 copies in workspace
// ---------------------------------------------------------------------------
__global__ void convert_w_kernel(const float* __restrict__ wq,
                                 const float* __restrict__ wo,
                                 f16* __restrict__ wq_h,
                                 f16* __restrict__ wo_h) {
    int i = blockIdx.x * blockDim.x + threadIdx.x;
    const int n4 = (512 * 512) / 4;
    const float4* src;
    f16* dst;
    if (i < n4) { src = (const float4*)wq; dst = wq_h; }
    else        { src = (const float4*)wo; dst = wo_h; i -= n4; }
    float4 v = src[i];
    f16* p = dst + (size_t)i * 4;
    p[0] = (f16)v.x; p[1] = (f16)v.y; p[2] = (f16)v.z; p[3] = (f16)v.w;
}

// ---------------------------------------------------------------------------
// Fused: out = cumprod8(cos(x @ Wq^T)) @ Wo^T, one block per 64 rows.
// - x tile (64x512 fp32) staged ONCE to LDS as f16 (XOR-swizzled granules)
// - phase 1: q = x @ Wq^T per 256-wide n-chunk; B-frags direct from L2
//   (prefetched 1 K-step ahead); NO barriers in K-loop (LDS read-only)
// - cumprod over 8-wide n-groups in-register (swapped-operand MFMA:
//   lane&15 = m, reg = n); meas kept in regs
// - barrier; meas regs -> same LDS buffer (swizzled); barrier
// - phase 2: out = meas @ Wo^T, same structure, f32x4 stores
// 256 threads = 4 waves; wave owns a 64m x 64n sub-tile per chunk.
// LDS 64 KB -> 2 blocks/CU; only 3 __syncthreads per block.
// ---------------------------------------------------------------------------
__global__ __launch_bounds__(256, 2)
void fused_kernel(const float* __restrict__ X,
                  const f16* __restrict__ Wq,
                  const f16* __restrict__ Wo,
                  float* __restrict__ Out) {
    __shared__ __align__(16) char T[BM * E * 2];   // 64 KB: x tile, then meas

    const int tid  = threadIdx.x;
    const int lane = tid & 63;
    const int wave = tid >> 6;
    const int fr   = lane & 15;    // fragment 16-index
    const int kq   = lane >> 4;    // k-quarter / n-quad
    const int m0   = blockIdx.x * BM;

    // ---- stage x tile: fp32 global -> f16 LDS, 16B granules, swizzled ----
    // granule g' = c8 ^ (row&7) breaks the 1KB-row-stride bank pattern.
#pragma unroll
    for (int r = 0; r < 4; ++r) {
        const int gid0 = r * 1024 + tid * 4;
        float4 buf[8];
#pragma unroll
        for (int c = 0; c < 4; ++c) {
            const int gid = gid0 + c;
            const int row = gid >> 6, c8 = gid & 63;
            const float* s = X + (size_t)(m0 + row) * E + c8 * 8;
            buf[c * 2]     = *(const float4*)s;
            buf[c * 2 + 1] = *(const float4*)(s + 4);
        }
#pragma unroll
        for (int c = 0; c < 4; ++c) {
            const int gid = gid0 + c;
            const int row = gid >> 6, c8 = gid & 63;
            f16x8 h;
#pragma unroll
            for (int q = 0; q < 4; ++q) {
                h[q]     = (f16)buf[c * 2][q];
                h[4 + q] = (f16)buf[c * 2 + 1][q];
            }
            *(f16x8*)(T + row * 1024 + ((c8 ^ (row & 7)) * 16)) = h;
        }
    }
    __syncthreads();

    // ---- phase 1: q = x @ Wq^T, cumprod(cos) -> meas regs ----
    f16x4 meas[NCHUNK][4][4];   // nc loop unrolled => static indexing

#pragma unroll
    for (int nc = 0; nc < NCHUNK; ++nc) {
        const int nb = nc * 256 + wave * 64;
        f32x4 acc[4][4] = {};
        f16x8 bcur[4], bnxt[4];
#pragma unroll
        for (int j = 0; j < 4; ++j)
            bcur[j] = *(const f16x8*)&Wq[(size_t)(nb + j * 16 + fr) * E + kq * 8];

        for (int t = 0; t < NT; ++t) {
            if (t + 1 < NT) {
#pragma unroll
                for (int j = 0; j < 4; ++j)
                    bnxt[j] = *(const f16x8*)&Wq[(size_t)(nb + j * 16 + fr) * E
                                                 + (t + 1) * 32 + kq * 8];
            }
            f16x8 afr[4];
#pragma unroll
            for (int i = 0; i < 4; ++i) {
                const int row = i * 16 + fr;
                const int c8  = t * 4 + kq;
                afr[i] = *(const f16x8*)(T + row * 1024 + ((c8 ^ (row & 7)) * 16));
            }
#pragma unroll
            for (int i = 0; i < 4; ++i)
#pragma unroll
                for (int j = 0; j < 4; ++j)
                    acc[i][j] = __builtin_amdgcn_mfma_f32_16x16x32_f16(
                        bcur[j], afr[i], acc[i][j], 0, 0, 0);
#pragma unroll
            for (int j = 0; j < 4; ++j) bcur[j] = bnxt[j];
        }

        // cumprod(cos) over 8-wide n-groups; reg axis = n, partner = lane^16
#pragma unroll
        for (int i = 0; i < 4; ++i)
#pragma unroll
            for (int j = 0; j < 4; ++j) {
                float c0 = __cosf(acc[i][j][0]);
                float c1 = c0 * __cosf(acc[i][j][1]);
                float c2 = c1 * __cosf(acc[i][j][2]);
                float c3 = c2 * __cosf(acc[i][j][3]);
                float ptot = __shfl_xor(c3, 16, 64);
                float f = (kq & 1) ? ptot : 1.0f;   // odd quad = upper half of 8-group
                meas[nc][i][j] = f16x4{ (f16)(c0 * f), (f16)(c1 * f),
                                        (f16)(c2 * f), (f16)(c3 * f) };
            }
    }

    __syncthreads();   // all waves done reading x; reuse T for meas

    // ---- meas regs -> LDS (same swizzle; f16x4 = half-granule writes) ----
#pragma unroll
    for (int nc = 0; nc < NCHUNK; ++nc) {
        const int nbase8 = (nc * 256 + wave * 64) >> 3;
#pragma unroll
        for (int i = 0; i < 4; ++i) {
            const int row = i * 16 + fr;
#pragma unroll
            for (int j = 0; j < 4; ++j) {
                const int c8 = nbase8 + j * 2 + (kq >> 1);
                *(f16x4*)(T + row * 1024 + ((c8 ^ (row & 7)) * 16) + (kq & 1) * 8)
                    = meas[nc][i][j];
            }
        }
    }
    __syncthreads();

    // ---- phase 2: out = meas @ Wo^T ----
#pragma unroll
    for (int fc = 0; fc < NCHUNK; ++fc) {
        const int fb = fc * 256 + wave * 64;
        f32x4 acc[4][4] = {};
        f16x8 bcur[4], bnxt[4];
#pragma unroll
        for (int j = 0; j < 4; ++j)
            bcur[j] = *(const f16x8*)&Wo[(size_t)(fb + j * 16 + fr) * E + kq * 8];

        for (int t = 0; t < NT; ++t) {
            if (t + 1 < NT) {
#pragma unroll
                for (int j = 0; j < 4; ++j)
                    bnxt[j] = *(const f16x8*)&Wo[(size_t)(fb + j * 16 + fr) * E
                                                 + (t + 1) * 32 + kq * 8];
            }
            f16x8 afr[4];
#pragma unroll
            for (int i = 0; i < 4; ++i) {
                const int row = i * 16 + fr;
                const int c8  = t * 4 + kq;
                afr[i] = *(const f16x8*)(T + row * 1024 + ((c8 ^ (row & 7)) * 16));
            }
#pragma unroll
            for (int i = 0; i < 4; ++i)
#pragma unroll
                for (int j = 0; j < 4; ++j)
                    acc[i][j] = __builtin_amdgcn_mfma_f32_16x16x32_f16(
                        bcur[j], afr[i], acc[i][j], 0, 0, 0);
#pragma unroll
            for (int j = 0; j < 4; ++j) bcur[j] = bnxt[j];
        }

        // store: lane&15 = m, reg quad = 4 consecutive f -> f32x4 stores
#pragma unroll
        for (int i = 0; i < 4; ++i) {
            const int row = m0 + i * 16 + fr;
#pragma unroll
            for (int j = 0; j < 4; ++j)
                *(f32x4*)&Out[(size_t)row * E + fb + j * 16 + kq * 4] = acc[i][j];
        }
    }
}

// ---------------------------------------------------------------------------
extern "C" void kernel_launch(void* const* d_in, const int* in_sizes, int n_in,
                              void* d_out, int out_size, void* d_ws, size_t ws_size,
                              hipStream_t stream) {
    const float* x  = (const float*)d_in[0];
    const float* Wq = (const float*)d_in[1];
    // d_in[2]=Wk, d_in[3]=Wv: dead compute in the reference
    const float* Wo = (const float*)d_in[4];

    const int M = in_sizes[0] / E;   // 32768

    f16* wq_h = (f16*)d_ws;
    f16* wo_h = wq_h + 512 * 512;

    convert_w_kernel<<<512, 256, 0, stream>>>(Wq, Wo, wq_h, wo_h);
    fused_kernel<<<M / BM, 256, 0, stream>>>(x, wq_h, wo_h, (float*)d_out);
}

// Round 6
// 85.064 us; speedup vs baseline: 1.0742x; 1.0742x over previous
//
#include <hip/hip_runtime.h>

typedef _Float16 f16;
typedef f16   f16x4 __attribute__((ext_vector_type(4)));
typedef f16   f16x8 __attribute__((ext_vector_type(8)));
typedef float f32x4 __attribute__((ext_vector_type(4)));

#define E 512
#define BM 32
#define NT 16            /* K-steps of 32 */

// ---------------------------------------------------------------------------
// Weight convert+pack: W (fp32 [512][512] row-major, y = x@W^T) ->
// f16 packed [t=k/32][n=512][k%32] so a wave's fragment load
// (16 n-rows x 16B) is 1KB fully contiguous.
// ---------------------------------------------------------------------------
__global__ void convert_w_kernel(const float* __restrict__ wq,
                                 const float* __restrict__ wo,
                                 f16* __restrict__ q_p,
                                 f16* __restrict__ o_p) {
    int i = blockIdx.x * blockDim.x + threadIdx.x;   // 65536 threads
    const int half = (512 * 512) / 8;                // 32768 groups of 8
    const float* src; f16* dst;
    if (i < half) { src = wq; dst = q_p; }
    else          { src = wo; dst = o_p; i -= half; }
    const int n = i >> 6, kg = i & 63;               // 8-elem k-group
    const float* s = src + (size_t)n * 512 + kg * 8;
    float4 a = *(const float4*)s, b = *(const float4*)(s + 4);
    f16x8 h;
#pragma unroll
    for (int q = 0; q < 4; ++q) { h[q] = (f16)a[q]; h[4 + q] = (f16)b[q]; }
    const int t = kg >> 2, w = kg & 3;
    *(f16x8*)&dst[(size_t)t * 16384 + n * 32 + w * 8] = h;
}

// ---------------------------------------------------------------------------
// Fused: out = cumprod8(cos(x @ Wq^T)) @ Wo^T.  One block = 32 rows, 8 waves.
//  - x tile fp32 -> f16 staged once: pre-swizzled global col, LINEAR LDS
//    write (conflict-free); reads use granule swizzle c8^(row&7) (2-way, free)
//  - phase 1: wave w owns n-cols [w*64, w*64+64); weight frags direct from
//    packed L2-resident Wq, prefetch 1 K-step ahead; NO barriers in K-loop
//  - swapped-operand MFMA: m = lane&15, n = (lane>>4)*4 + reg ->
//    cumprod(cos) = 3 muls + 1 shfl_xor(16); meas -> Ms LDS immediately
//  - phase 2: same structure on Ms/Wo; f32x4 stores (4 kq-lanes/row = 64B)
// LDS 64 KB/block -> 2 blocks/CU = 4 waves/SIMD; live regs ~90 -> no spills.
// ---------------------------------------------------------------------------
__global__ __launch_bounds__(512, 4)
void fused_kernel(const float* __restrict__ X,
                  const f16* __restrict__ Wq,   // packed [16][512][32]
                  const f16* __restrict__ Wo,   // packed [16][512][32]
                  float* __restrict__ Out) {
    __shared__ __align__(16) char T[64 * 1024];
    char* Xs = T;                 // 32 KB: x tile f16, swizzled granules
    char* Ms = T + 32 * 1024;     // 32 KB: meas f16, same layout

    const int tid  = threadIdx.x;
    const int lane = tid & 63;
    const int wave = tid >> 6;        // 0..7
    const int fr   = lane & 15;
    const int kq   = lane >> 4;

    // XCD-chunked bijective swizzle (gridDim.x % 8 == 0)
    const int bid = blockIdx.x;
    const int chunk = gridDim.x >> 3;
    const int swz = (bid & 7) * chunk + (bid >> 3);
    const int m0 = swz * BM;

    // ---- stage x: wave w -> rows w*4..w*4+3 ----
    float4 xa[4], xb[4];
#pragma unroll
    for (int c = 0; c < 4; ++c) {
        const int row = wave * 4 + c;
        const int col = (lane ^ (row & 7)) * 8;      // pre-swizzled source col
        const float* s = X + (size_t)(m0 + row) * E + col;
        xa[c] = *(const float4*)s;
        xb[c] = *(const float4*)(s + 4);
    }
#pragma unroll
    for (int c = 0; c < 4; ++c) {
        const int row = wave * 4 + c;
        f16x8 h;
#pragma unroll
        for (int q = 0; q < 4; ++q) { h[q] = (f16)xa[c][q]; h[4 + q] = (f16)xb[c][q]; }
        *(f16x8*)(Xs + row * 1024 + lane * 16) = h;  // linear: conflict-free
    }
    __syncthreads();

    // ---- phase 1: q = x @ Wq^T -> meas ----
    {
        const int nb = wave * 64;
        f32x4 acc[2][4] = {};
        f16x8 bcur[4], bnxt[4];
        const f16* wbase = Wq + (size_t)(nb + fr) * 32 + kq * 8;
#pragma unroll
        for (int j = 0; j < 4; ++j)
            bcur[j] = *(const f16x8*)(wbase + j * 512);

        for (int t = 0; t < NT; ++t) {
            if (t + 1 < NT) {
#pragma unroll
                for (int j = 0; j < 4; ++j)
                    bnxt[j] = *(const f16x8*)(wbase + (size_t)(t + 1) * 16384 + j * 512);
            }
            f16x8 afr[2];
#pragma unroll
            for (int i = 0; i < 2; ++i) {
                const int row = i * 16 + fr;
                const int c8  = t * 4 + kq;
                afr[i] = *(const f16x8*)(Xs + row * 1024 + ((c8 ^ (row & 7)) * 16));
            }
#pragma unroll
            for (int i = 0; i < 2; ++i)
#pragma unroll
                for (int j = 0; j < 4; ++j)
                    acc[i][j] = __builtin_amdgcn_mfma_f32_16x16x32_f16(
                        bcur[j], afr[i], acc[i][j], 0, 0, 0);
#pragma unroll
            for (int j = 0; j < 4; ++j) bcur[j] = bnxt[j];
        }

        // cumprod(cos) over 8-wide n-groups; partner lane^16 holds other half
#pragma unroll
        for (int i = 0; i < 2; ++i) {
            const int row = i * 16 + fr;
#pragma unroll
            for (int j = 0; j < 4; ++j) {
                float c0 = __cosf(acc[i][j][0]);
                float c1 = c0 * __cosf(acc[i][j][1]);
                float c2 = c1 * __cosf(acc[i][j][2]);
                float c3 = c2 * __cosf(acc[i][j][3]);
                float ptot = __shfl_xor(c3, 16, 64);
                float f = (kq & 1) ? ptot : 1.0f;    // odd quad = upper half
                f16x4 v = { (f16)(c0 * f), (f16)(c1 * f),
                            (f16)(c2 * f), (f16)(c3 * f) };
                const int c8 = (nb >> 3) + j * 2 + (kq >> 1);
                *(f16x4*)(Ms + row * 1024 + ((c8 ^ (row & 7)) * 16) + (kq & 1) * 8) = v;
            }
        }
    }
    __syncthreads();

    // ---- phase 2: out = meas @ Wo^T ----
    {
        const int fb = wave * 64;
        f32x4 acc[2][4] = {};
        f16x8 bcur[4], bnxt[4];
        const f16* wbase = Wo + (size_t)(fb + fr) * 32 + kq * 8;
#pragma unroll
        for (int j = 0; j < 4; ++j)
            bcur[j] = *(const f16x8*)(wbase + j * 512);

        for (int t = 0; t < NT; ++t) {
            if (t + 1 < NT) {
#pragma unroll
                for (int j = 0; j < 4; ++j)
                    bnxt[j] = *(const f16x8*)(wbase + (size_t)(t + 1) * 16384 + j * 512);
            }
            f16x8 afr[2];
#pragma unroll
            for (int i = 0; i < 2; ++i) {
                const int row = i * 16 + fr;
                const int c8  = t * 4 + kq;
                afr[i] = *(const f16x8*)(Ms + row * 1024 + ((c8 ^ (row & 7)) * 16));
            }
#pragma unroll
            for (int i = 0; i < 2; ++i)
#pragma unroll
                for (int j = 0; j < 4; ++j)
                    acc[i][j] = __builtin_amdgcn_mfma_f32_16x16x32_f16(
                        bcur[j], afr[i], acc[i][j], 0, 0, 0);
#pragma unroll
            for (int j = 0; j < 4; ++j) bcur[j] = bnxt[j];
        }

        // store: 4 kq-lanes per row write 64B contiguous per (i,j)
#pragma unroll
        for (int i = 0; i < 2; ++i) {
            const int row = m0 + i * 16 + fr;
#pragma unroll
            for (int j = 0; j < 4; ++j)
                *(f32x4*)&Out[(size_t)row * E + fb + j * 16 + kq * 4] = acc[i][j];
        }
    }
}

// ---------------------------------------------------------------------------
extern "C" void kernel_launch(void* const* d_in, const int* in_sizes, int n_in,
                              void* d_out, int out_size, void* d_ws, size_t ws_size,
                              hipStream_t stream) {
    const float* x  = (const float*)d_in[0];
    const float* Wq = (const float*)d_in[1];
    // d_in[2]=Wk, d_in[3]=Wv: dead compute in the reference
    const float* Wo = (const float*)d_in[4];

    const int M = in_sizes[0] / E;   // 32768

    f16* wq_p = (f16*)d_ws;          // 512 KB packed
    f16* wo_p = wq_p + 512 * 512;    // 512 KB packed

    convert_w_kernel<<<256, 256, 0, stream>>>(Wq, Wo, wq_p, wo_p);
    fused_kernel<<<M / BM, 512, 0, stream>>>(x, wq_p, wo_p, (float*)d_out);
}

// Round 7
// 64.350 us; speedup vs baseline: 1.4199x; 1.3219x over previous
//
#include <hip/hip_runtime.h>

typedef _Float16 f16;
typedef f16   f16x4 __attribute__((ext_vector_type(4)));
typedef f16   f16x8 __attribute__((ext_vector_type(8)));
typedef float f32x4 __attribute__((ext_vector_type(4)));

#define E 512
#define BM 64
#define NT 16            /* K-steps of 32 */

// ---------------------------------------------------------------------------
// Weight convert+pack: W (fp32 [512][512] row-major, y = x@W^T) ->
// f16 packed [t=k/32][n=512][k%32] so a wave's fragment load
// (16 n-rows x 16B) is 1KB fully contiguous.
// ---------------------------------------------------------------------------
__global__ void convert_w_kernel(const float* __restrict__ wq,
                                 const float* __restrict__ wo,
                                 f16* __restrict__ q_p,
                                 f16* __restrict__ o_p) {
    int i = blockIdx.x * blockDim.x + threadIdx.x;   // 65536 threads
    const int half = (512 * 512) / 8;                // 32768 groups of 8
    const float* src; f16* dst;
    if (i < half) { src = wq; dst = q_p; }
    else          { src = wo; dst = o_p; i -= half; }
    const int n = i >> 6, kg = i & 63;               // 8-elem k-group
    const float* s = src + (size_t)n * 512 + kg * 8;
    float4 a = *(const float4*)s, b = *(const float4*)(s + 4);
    f16x8 h;
#pragma unroll
    for (int q = 0; q < 4; ++q) { h[q] = (f16)a[q]; h[4 + q] = (f16)b[q]; }
    const int t = kg >> 2, w = kg & 3;
    *(f16x8*)&dst[(size_t)t * 16384 + n * 32 + w * 8] = h;
}

// ---------------------------------------------------------------------------
// Fused: out = cumprod8(cos(x @ Wq^T)) @ Wo^T.  One block = 64 rows, 8 waves.
// Wave tile 64m x 64n: 4 A-frags x 4 B-frags = 16 MFMA per 4KB weight frags
// (64 FLOP/B on the L2 weight path -> 0.5 GB total, under the HBM floor).
//  - x tile fp32 -> f16 staged once (pre-swizzled global col, linear LDS write)
//  - weight frags direct from packed L2-resident W, ping-pong prefetch depth 2
//    (full unroll -> static indexing), NO barriers inside K-loops
//  - swapped-operand MFMA: m = lane&15, n = (lane>>4)*4 + reg ->
//    cumprod(cos) = 3 muls + 1 shfl_xor(16); meas -> Ms immediately
//  - phase 2 on Ms/Wo, f32x4 stores
// LDS 128 KB (64 static + 64 dynamic) -> 1 block/CU, 8 waves = 2/SIMD.
// ---------------------------------------------------------------------------
__global__ __launch_bounds__(512, 2)
void fused_kernel(const float* __restrict__ X,
                  const f16* __restrict__ Wq,   // packed [16][512][32]
                  const f16* __restrict__ Wo,   // packed [16][512][32]
                  float* __restrict__ Out) {
    __shared__ __align__(16) char Xs[64 * 1024];   // x tile f16, swizzled granules
    extern __shared__ __align__(16) char Ms[];     // meas f16, same layout (64 KB dyn)

    const int tid  = threadIdx.x;
    const int lane = tid & 63;
    const int wave = tid >> 6;        // 0..7
    const int fr   = lane & 15;
    const int kq   = lane >> 4;

    // XCD-chunked bijective swizzle (gridDim.x % 8 == 0)
    const int bid = blockIdx.x;
    const int chunk = gridDim.x >> 3;
    const int swz = (bid & 7) * chunk + (bid >> 3);
    const int m0 = swz * BM;

    // ---- stage x: wave w -> rows w*8..w*8+7 ----
    {
        float4 xa[8], xb[8];
#pragma unroll
        for (int c = 0; c < 8; ++c) {
            const int row = wave * 8 + c;
            const int col = (lane ^ (row & 7)) * 8;      // pre-swizzled source col
            const float* s = X + (size_t)(m0 + row) * E + col;
            xa[c] = *(const float4*)s;
            xb[c] = *(const float4*)(s + 4);
        }
#pragma unroll
        for (int c = 0; c < 8; ++c) {
            const int row = wave * 8 + c;
            f16x8 h;
#pragma unroll
            for (int q = 0; q < 4; ++q) { h[q] = (f16)xa[c][q]; h[4 + q] = (f16)xb[c][q]; }
            *(f16x8*)(Xs + row * 1024 + lane * 16) = h;  // linear: conflict-free
        }
    }
    __syncthreads();

    // ---- phase 1: q = x @ Wq^T -> meas (wave owns n-cols [wave*64, +64)) ----
    {
        const int nb = wave * 64;
        f32x4 acc[4][4] = {};
        f16x8 bw[2][4];
        const f16* wbase = Wq + (size_t)(nb + fr) * 32 + kq * 8;
#pragma unroll
        for (int j = 0; j < 4; ++j) bw[0][j] = *(const f16x8*)(wbase + j * 512);
#pragma unroll
        for (int j = 0; j < 4; ++j) bw[1][j] = *(const f16x8*)(wbase + 16384 + j * 512);

#pragma unroll
        for (int t = 0; t < NT; ++t) {
            f16x8 afr[4];
#pragma unroll
            for (int i = 0; i < 4; ++i) {
                const int row = i * 16 + fr;
                const int c8  = t * 4 + kq;
                afr[i] = *(const f16x8*)(Xs + row * 1024 + ((c8 ^ (row & 7)) * 16));
            }
#pragma unroll
            for (int i = 0; i < 4; ++i)
#pragma unroll
                for (int j = 0; j < 4; ++j)
                    acc[i][j] = __builtin_amdgcn_mfma_f32_16x16x32_f16(
                        bw[t & 1][j], afr[i], acc[i][j], 0, 0, 0);
            if (t + 2 < NT) {   // refill the buffer just consumed (prefetch depth 2)
#pragma unroll
                for (int j = 0; j < 4; ++j)
                    bw[t & 1][j] = *(const f16x8*)(wbase + (size_t)(t + 2) * 16384 + j * 512);
            }
        }

        // cumprod(cos) over 8-wide n-groups; partner lane^16 holds other half
#pragma unroll
        for (int i = 0; i < 4; ++i) {
            const int row = i * 16 + fr;
#pragma unroll
            for (int j = 0; j < 4; ++j) {
                float c0 = __cosf(acc[i][j][0]);
                float c1 = c0 * __cosf(acc[i][j][1]);
                float c2 = c1 * __cosf(acc[i][j][2]);
                float c3 = c2 * __cosf(acc[i][j][3]);
                float ptot = __shfl_xor(c3, 16, 64);
                float f = (kq & 1) ? ptot : 1.0f;    // odd quad = upper half
                f16x4 v = { (f16)(c0 * f), (f16)(c1 * f),
                            (f16)(c2 * f), (f16)(c3 * f) };
                const int c8 = (nb >> 3) + j * 2 + (kq >> 1);
                *(f16x4*)(Ms + row * 1024 + ((c8 ^ (row & 7)) * 16) + (kq & 1) * 8) = v;
            }
        }
    }
    __syncthreads();

    // ---- phase 2: out = meas @ Wo^T (wave owns f-cols [wave*64, +64)) ----
    {
        const int fb = wave * 64;
        f32x4 acc[4][4] = {};
        f16x8 bw[2][4];
        const f16* wbase = Wo + (size_t)(fb + fr) * 32 + kq * 8;
#pragma unroll
        for (int j = 0; j < 4; ++j) bw[0][j] = *(const f16x8*)(wbase + j * 512);
#pragma unroll
        for (int j = 0; j < 4; ++j) bw[1][j] = *(const f16x8*)(wbase + 16384 + j * 512);

#pragma unroll
        for (int t = 0; t < NT; ++t) {
            f16x8 afr[4];
#pragma unroll
            for (int i = 0; i < 4; ++i) {
                const int row = i * 16 + fr;
                const int c8  = t * 4 + kq;
                afr[i] = *(const f16x8*)(Ms + row * 1024 + ((c8 ^ (row & 7)) * 16));
            }
#pragma unroll
            for (int i = 0; i < 4; ++i)
#pragma unroll
                for (int j = 0; j < 4; ++j)
                    acc[i][j] = __builtin_amdgcn_mfma_f32_16x16x32_f16(
                        bw[t & 1][j], afr[i], acc[i][j], 0, 0, 0);
            if (t + 2 < NT) {
#pragma unroll
                for (int j = 0; j < 4; ++j)
                    bw[t & 1][j] = *(const f16x8*)(wbase + (size_t)(t + 2) * 16384 + j * 512);
            }
        }

        // store: 4 kq-lanes per row write 64B contiguous per (i,j)
#pragma unroll
        for (int i = 0; i < 4; ++i) {
            const int row = m0 + i * 16 + fr;
#pragma unroll
            for (int j = 0; j < 4; ++j)
                *(f32x4*)&Out[(size_t)row * E + fb + j * 16 + kq * 4] = acc[i][j];
        }
    }
}

// ---------------------------------------------------------------------------
extern "C" void kernel_launch(void* const* d_in, const int* in_sizes, int n_in,
                              void* d_out, int out_size, void* d_ws, size_t ws_size,
                              hipStream_t stream) {
    const float* x  = (const float*)d_in[0];
    const float* Wq = (const float*)d_in[1];
    // d_in[2]=Wk, d_in[3]=Wv: dead compute in the reference
    const float* Wo = (const float*)d_in[4];

    const int M = in_sizes[0] / E;   // 32768

    f16* wq_p = (f16*)d_ws;          // 512 KB packed
    f16* wo_p = wq_p + 512 * 512;    // 512 KB packed

    convert_w_kernel<<<256, 256, 0, stream>>>(Wq, Wo, wq_p, wo_p);
    fused_kernel<<<M / BM, 512, 64 * 1024, stream>>>(x, wq_p, wo_p, (float*)d_out);
}

// Round 8
// 59.803 us; speedup vs baseline: 1.5279x; 1.0760x over previous
//
#include <hip/hip_runtime.h>

typedef _Float16 f16;
typedef f16   f16x4 __attribute__((ext_vector_type(4)));
typedef f16   f16x8 __attribute__((ext_vector_type(8)));
typedef float f32x4 __attribute__((ext_vector_type(4)));

#define E 512
#define BM 64
#define NT 16            /* K-steps of 32 */

// ---------------------------------------------------------------------------
// Weight convert+pack: W (fp32 [512][512] row-major, y = x@W^T) ->
// f16 packed [t=k/32][n=512][k%32]: a wave's fragment load is 1KB contiguous.
// ---------------------------------------------------------------------------
__global__ void convert_w_kernel(const float* __restrict__ wq,
                                 const float* __restrict__ wo,
                                 f16* __restrict__ q_p,
                                 f16* __restrict__ o_p) {
    int i = blockIdx.x * blockDim.x + threadIdx.x;   // 65536 threads
    const int half = (512 * 512) / 8;                // 32768 groups of 8
    const float* src; f16* dst;
    if (i < half) { src = wq; dst = q_p; }
    else          { src = wo; dst = o_p; i -= half; }
    const int n = i >> 6, kg = i & 63;               // 8-elem k-group
    const float* s = src + (size_t)n * 512 + kg * 8;
    float4 a = *(const float4*)s, b = *(const float4*)(s + 4);
    f16x8 h;
#pragma unroll
    for (int q = 0; q < 4; ++q) { h[q] = (f16)a[q]; h[4 + q] = (f16)b[q]; }
    const int t = kg >> 2, w = kg & 3;
    *(f16x8*)&dst[(size_t)t * 16384 + n * 32 + w * 8] = h;
}

// ---------------------------------------------------------------------------
// Fused: out = cumprod8(cos(x @ Wq^T)) @ Wo^T.  One block = 64 rows, 8 waves.
// Wave tile 64m x 64n (16 MFMA / 4KB weight frags = 64 FLOP/B on L2 path).
// SINGLE 64 KB LDS buffer, aliased:
//   stage x -> T; barrier; phase1 reads T (acc in regs, NO K-loop barriers);
//   cumprod -> 32 transient VGPRs; barrier; meas overwrites T; barrier;
//   phase2 reads T; f32x4 stores.
// 64 KB -> 2 blocks/CU = 4 waves/SIMD (the round-7 limiter was 2/SIMD).
// Weight frags direct from packed L2-resident W, ping-pong prefetch depth 2.
// Swapped-operand MFMA: m = lane&15, n = (lane>>4)*4 + reg.
// ---------------------------------------------------------------------------
__global__ __launch_bounds__(512, 4)
void fused_kernel(const float* __restrict__ X,
                  const f16* __restrict__ Wq,   // packed [16][512][32]
                  const f16* __restrict__ Wo,   // packed [16][512][32]
                  float* __restrict__ Out) {
    __shared__ __align__(16) char T[64 * 1024];   // x tile, then meas (aliased)

    const int tid  = threadIdx.x;
    const int lane = tid & 63;
    const int wave = tid >> 6;        // 0..7
    const int fr   = lane & 15;
    const int kq   = lane >> 4;

    // XCD-chunked bijective swizzle (gridDim.x % 8 == 0)
    const int bid = blockIdx.x;
    const int chunk = gridDim.x >> 3;
    const int swz = (bid & 7) * chunk + (bid >> 3);
    const int m0 = swz * BM;

    // ---- stage x: wave w -> rows w*8..w*8+7 (pre-swizzled col, linear write) ----
    {
        float4 xa[8], xb[8];
#pragma unroll
        for (int c = 0; c < 8; ++c) {
            const int row = wave * 8 + c;
            const int col = (lane ^ (row & 7)) * 8;
            const float* s = X + (size_t)(m0 + row) * E + col;
            xa[c] = *(const float4*)s;
            xb[c] = *(const float4*)(s + 4);
        }
#pragma unroll
        for (int c = 0; c < 8; ++c) {
            const int row = wave * 8 + c;
            f16x8 h;
#pragma unroll
            for (int q = 0; q < 4; ++q) { h[q] = (f16)xa[c][q]; h[4 + q] = (f16)xb[c][q]; }
            *(f16x8*)(T + row * 1024 + lane * 16) = h;
        }
    }
    __syncthreads();

    // ---- phase 1: q = x @ Wq^T -> meas regs (wave owns n-cols [wave*64,+64)) ----
    f16x4 mr[4][4];                    // transient meas, 32 VGPR
    {
        const int nb = wave * 64;
        f32x4 acc[4][4] = {};
        f16x8 bw[2][4];
        const f16* wbase = Wq + (size_t)(nb + fr) * 32 + kq * 8;
#pragma unroll
        for (int j = 0; j < 4; ++j) bw[0][j] = *(const f16x8*)(wbase + j * 512);
#pragma unroll
        for (int j = 0; j < 4; ++j) bw[1][j] = *(const f16x8*)(wbase + 16384 + j * 512);

#pragma unroll
        for (int t = 0; t < NT; ++t) {
            f16x8 afr[4];
#pragma unroll
            for (int i = 0; i < 4; ++i) {
                const int row = i * 16 + fr;
                const int c8  = t * 4 + kq;
                afr[i] = *(const f16x8*)(T + row * 1024 + ((c8 ^ (row & 7)) * 16));
            }
#pragma unroll
            for (int i = 0; i < 4; ++i)
#pragma unroll
                for (int j = 0; j < 4; ++j)
                    acc[i][j] = __builtin_amdgcn_mfma_f32_16x16x32_f16(
                        bw[t & 1][j], afr[i], acc[i][j], 0, 0, 0);
            if (t + 2 < NT) {   // refill consumed buffer (prefetch depth 2)
#pragma unroll
                for (int j = 0; j < 4; ++j)
                    bw[t & 1][j] = *(const f16x8*)(wbase + (size_t)(t + 2) * 16384 + j * 512);
            }
        }

        // cumprod(cos) over 8-wide n-groups; partner lane^16 holds other half
#pragma unroll
        for (int i = 0; i < 4; ++i)
#pragma unroll
            for (int j = 0; j < 4; ++j) {
                float c0 = __cosf(acc[i][j][0]);
                float c1 = c0 * __cosf(acc[i][j][1]);
                float c2 = c1 * __cosf(acc[i][j][2]);
                float c3 = c2 * __cosf(acc[i][j][3]);
                float ptot = __shfl_xor(c3, 16, 64);
                float f = (kq & 1) ? ptot : 1.0f;    // odd quad = upper half
                mr[i][j] = f16x4{ (f16)(c0 * f), (f16)(c1 * f),
                                  (f16)(c2 * f), (f16)(c3 * f) };
            }
    }
    __syncthreads();   // all waves done READING x from T

    // ---- meas regs -> T (same swizzled layout) ----
    {
        const int nb8 = (wave * 64) >> 3;
#pragma unroll
        for (int i = 0; i < 4; ++i) {
            const int row = i * 16 + fr;
#pragma unroll
            for (int j = 0; j < 4; ++j) {
                const int c8 = nb8 + j * 2 + (kq >> 1);
                *(f16x4*)(T + row * 1024 + ((c8 ^ (row & 7)) * 16) + (kq & 1) * 8)
                    = mr[i][j];
            }
        }
    }
    __syncthreads();

    // ---- phase 2: out = meas @ Wo^T (wave owns f-cols [wave*64,+64)) ----
    {
        const int fb = wave * 64;
        f32x4 acc[4][4] = {};
        f16x8 bw[2][4];
        const f16* wbase = Wo + (size_t)(fb + fr) * 32 + kq * 8;
#pragma unroll
        for (int j = 0; j < 4; ++j) bw[0][j] = *(const f16x8*)(wbase + j * 512);
#pragma unroll
        for (int j = 0; j < 4; ++j) bw[1][j] = *(const f16x8*)(wbase + 16384 + j * 512);

#pragma unroll
        for (int t = 0; t < NT; ++t) {
            f16x8 afr[4];
#pragma unroll
            for (int i = 0; i < 4; ++i) {
                const int row = i * 16 + fr;
                const int c8  = t * 4 + kq;
                afr[i] = *(const f16x8*)(T + row * 1024 + ((c8 ^ (row & 7)) * 16));
            }
#pragma unroll
            for (int i = 0; i < 4; ++i)
#pragma unroll
                for (int j = 0; j < 4; ++j)
                    acc[i][j] = __builtin_amdgcn_mfma_f32_16x16x32_f16(
                        bw[t & 1][j], afr[i], acc[i][j], 0, 0, 0);
            if (t + 2 < NT) {
#pragma unroll
                for (int j = 0; j < 4; ++j)
                    bw[t & 1][j] = *(const f16x8*)(wbase + (size_t)(t + 2) * 16384 + j * 512);
            }
        }

        // store: 4 kq-lanes per row write 64B contiguous per (i,j)
#pragma unroll
        for (int i = 0; i < 4; ++i) {
            const int row = m0 + i * 16 + fr;
#pragma unroll
            for (int j = 0; j < 4; ++j)
                *(f32x4*)&Out[(size_t)row * E + fb + j * 16 + kq * 4] = acc[i][j];
        }
    }
}

// ---------------------------------------------------------------------------
extern "C" void kernel_launch(void* const* d_in, const int* in_sizes, int n_in,
                              void* d_out, int out_size, void* d_ws, size_t ws_size,
                              hipStream_t stream) {
    const float* x  = (const float*)d_in[0];
    const float* Wq = (const float*)d_in[1];
    // d_in[2]=Wk, d_in[3]=Wv: dead compute in the reference
    const float* Wo = (const float*)d_in[4];

    const int M = in_sizes[0] / E;   // 32768

    f16* wq_p = (f16*)d_ws;          // 512 KB packed
    f16* wo_p = wq_p + 512 * 512;    // 512 KB packed

    convert_w_kernel<<<256, 256, 0, stream>>>(Wq, Wo, wq_p, wo_p);
    fused_kernel<<<M / BM, 512, 0, stream>>>(x, wq_p, wo_p, (float*)d_out);
}